// Round 16
// baseline (307.120 us; speedup 1.0000x reference)
//
#include <hip/hip_runtime.h>
#include <math.h>

#define CI 256
#define CO 256
#define HWN 4096  // H*W

typedef short bf16x8 __attribute__((ext_vector_type(8)));
typedef float f32x4 __attribute__((ext_vector_type(4)));

__device__ inline unsigned pk2(float a, float b) {  // RNE pack 2 f32 -> 2 bf16
  unsigned ua = __float_as_uint(a), ub = __float_as_uint(b);
  ua += 0x7fff + ((ua >> 16) & 1);
  ub += 0x7fff + ((ub >> 16) & 1);
  return (ua >> 16) | (ub & 0xffff0000u);
}

// Raw barrier that does NOT drain vmcnt (keeps prefetch loads in flight).
#define PIPE_BARRIER()                                    \
  do {                                                    \
    __builtin_amdgcn_sched_barrier(0);                    \
    asm volatile("s_waitcnt lgkmcnt(0)" ::: "memory");    \
    __builtin_amdgcn_s_barrier();                         \
    __builtin_amdgcn_sched_barrier(0);                    \
  } while (0)

// ---------------------------------------------------------------------------
// Kernel 0: fused prep. bid<4096: x f32->bf16; 4096..4351: wT; 4352..4383: wTo.
// ---------------------------------------------------------------------------
__global__ __launch_bounds__(256) void k_prep(
    const float* __restrict__ x, const float* __restrict__ wgt,
    const float* __restrict__ ow, const float* __restrict__ mw,
    unsigned short* __restrict__ wT, unsigned short* __restrict__ wTo,
    unsigned short* __restrict__ xhp) {
  const int bid = blockIdx.x, tid = threadIdx.x;
  if (bid < 4096) {
    int i = bid * 256 + tid;
    const float4* xf = (const float4*)x;
    float4 a = xf[2 * i], b = xf[2 * i + 1];
    ((uint4*)xhp)[i] = make_uint4(pk2(a.x, a.y), pk2(a.z, a.w), pk2(b.x, b.y),
                                  pk2(b.z, b.w));
  } else if (bid < 4352) {
    int o = bid - 4096, c = tid;
    const float* wp = wgt + o * 2304 + c * 9;
    float v[9];
#pragma unroll
    for (int t = 0; t < 9; ++t) v[t] = wp[t];
#pragma unroll
    for (int t = 0; t < 9; ++t) {
      unsigned u = __float_as_uint(v[t]);
      u += 0x7fff + ((u >> 16) & 1);
      wT[(t << 16) + (o << 8) + c] = (unsigned short)(u >> 16);
    }
  } else {
    int o = bid - 4352, c = tid;
    float v[9];
    if (o < 18) {
      const float* wp = ow + o * 2304 + c * 9;
#pragma unroll
      for (int t = 0; t < 9; ++t) v[t] = wp[t];
    } else if (o < 27) {
      const float* wp = mw + (o - 18) * 2304 + c * 9;
#pragma unroll
      for (int t = 0; t < 9; ++t) v[t] = wp[t];
    } else {
#pragma unroll
      for (int t = 0; t < 9; ++t) v[t] = 0.f;
    }
#pragma unroll
    for (int t = 0; t < 9; ++t) {
      unsigned u = __float_as_uint(v[t]);
      u += 0x7fff + ((u >> 16) & 1);
      wTo[(t << 13) + (o << 8) + c] = (unsigned short)(u >> 16);
    }
  }
}

// ---------------------------------------------------------------------------
// FUSED kernel: R15-exact except __launch_bounds__(512,6) -> 3 blocks/CU
// (LDS 47.9 KB x 3 = 143.6 KB < 160 KB; VGPR 60 fits 24 waves/CU easily).
// Phase 0 = offset conv in-LDS; phase 1 = R12-exact main gather-GEMM.
// ---------------------------------------------------------------------------
__global__ __launch_bounds__(512, 6) void k_fused2(
    const unsigned short* __restrict__ xh, const unsigned short* __restrict__ wT,
    const unsigned short* __restrict__ wTo, const float* __restrict__ ob,
    const float* __restrict__ mb, float* __restrict__ out,
    float* __restrict__ psum, float* __restrict__ psq) {
  __shared__ __align__(16) char smem[47872];
  uint2* s_cw = (uint2*)smem;               // [9][64] phase-1 corner w
  ushort2* s_ci = (ushort2*)(smem + 4608);  // [9][64] phase-1 pair bases
  char* sA = smem + 6912;                   // phase-1 A (8 KB)
  char* sB = smem + 15104;                  // phase-1 B (32 KB)
  float* tr = (float*)(smem + 6912);        // store-transpose reuse
  char* sA0 = smem + 6912;                  // phase-0 group-0 A (8 KB)
  char* sA1 = smem + 15104;                 // phase-0 group-1 A (8 KB)
  char* sB0 = smem + 23296;                 // phase-0 group-0 B (4 KB)
  char* sB1 = smem + 27392;                 // phase-0 group-1 B (4 KB)
  float* s_red = (float*)(smem + 6912);     // phase-0 reduce (after loop)
  float* s_off = (float*)(smem + 31488);    // [27][64] offsets (6.9 KB)

  const int tid = threadIdx.x;
  const int mblk = blockIdx.x;  // b*64 + h
  const int b = mblk >> 6, h = mblk & 63;
  const int lane = tid & 63;
  const int wv = tid >> 6;
  const char* xbh = (const char*)(xh + (size_t)b * (CI * HWN));

  // ===================== PHASE 0: offset conv (27 ch) =====================
  {
    const int grp = wv >> 2;  // 0: cq 0-1, 1: cq 2-3
    const int lw = wv & 3;
    const int gtid = tid & 255;
    const int px = lane;
    char* sAg = grp ? sA1 : sA0;
    char* sBg = grp ? sB1 : sB0;
    f32x4 pacc[2];
    pacc[0] = (f32x4){0.f, 0.f, 0.f, 0.f};
    pacc[1] = (f32x4){0.f, 0.f, 0.f, 0.f};

    unsigned rxu[16];
    float cwA, cwB;
    {
      int y0 = h - 1, x0 = px - 1;
      float w = (((unsigned)y0 < 64u) && ((unsigned)x0 < 64u)) ? 1.f : 0.f;
      int y0c = min(max(y0, 0), 63);
      int xp = min(max(x0, 0), 62);
      int s0 = min(max(x0, 0), 63) - xp;
      cwA = s0 ? 0.f : w;
      cwB = s0 ? w : 0.f;
      int ci = y0c * 64 + xp;
#pragma unroll
      for (int g2 = 0; g2 < 2; ++g2) {
        int g = lw + (g2 << 2);
#pragma unroll
        for (int j = 0; j < 8; ++j) {
          int c = ((grp << 1) << 6) + (g << 3) + j;
          __builtin_memcpy(&rxu[(g2 << 3) + j], xbh + (((c << 12) + ci) << 1),
                           4);
        }
      }
    }

#pragma unroll 1
    for (int t = 0; t < 18; ++t) {
      const int cqi = t / 9;
      const int tap = t - cqi * 9;
      const int cq = (grp << 1) + cqi;
#pragma unroll
      for (int g2 = 0; g2 < 2; ++g2) {
        unsigned pkv[4];
#pragma unroll
        for (int j2 = 0; j2 < 4; ++j2) {
          unsigned d0 = rxu[(g2 << 3) + (j2 << 1)];
          unsigned d1 = rxu[(g2 << 3) + (j2 << 1) + 1];
          float v0 = cwA * __uint_as_float(d0 << 16);
          v0 = fmaf(cwB, __uint_as_float(d0 & 0xffff0000u), v0);
          float v1 = cwA * __uint_as_float(d1 << 16);
          v1 = fmaf(cwB, __uint_as_float(d1 & 0xffff0000u), v1);
          pkv[j2] = pk2(v0, v1);
        }
        int g = lw + (g2 << 2);
        *(uint4*)(sAg + (px << 7) + ((g ^ (px & 7)) << 4)) =
            make_uint4(pkv[0], pkv[1], pkv[2], pkv[3]);
      }
      {
        int o = gtid >> 3, seg = gtid & 7;
        uint4 v = *(const uint4*)(wTo + (tap << 13) + (o << 8) + (cq << 6) +
                                  (seg << 3));
        *(uint4*)(sBg + (o << 7) + ((seg ^ (o & 7)) << 4)) = v;
      }
      {
        const int tn = t < 17 ? t + 1 : 17;
        const int cqni = tn / 9;
        const int tapn = tn - cqni * 9;
        const int cqn = (grp << 1) + cqni;
        int ky = tapn / 3, kx = tapn - 3 * ky;
        int y0 = h - 1 + ky, x0 = px - 1 + kx;
        float w = (((unsigned)y0 < 64u) && ((unsigned)x0 < 64u)) ? 1.f : 0.f;
        int y0c = min(max(y0, 0), 63);
        int xp = min(max(x0, 0), 62);
        int s0 = min(max(x0, 0), 63) - xp;
        float cwAn = s0 ? 0.f : w;
        float cwBn = s0 ? w : 0.f;
        int ci = y0c * 64 + xp;
#pragma unroll
        for (int g2 = 0; g2 < 2; ++g2) {
          int g = lw + (g2 << 2);
#pragma unroll
          for (int j = 0; j < 8; ++j) {
            int c = (cqn << 6) + (g << 3) + j;
            __builtin_memcpy(&rxu[(g2 << 3) + j],
                             xbh + (((c << 12) + ci) << 1), 4);
          }
        }
        cwA = cwAn;
        cwB = cwBn;
      }
      PIPE_BARRIER();
#pragma unroll
      for (int ks = 0; ks < 2; ++ks) {
        int arow = (lw << 4) + (lane & 15);
        int aslt = ((ks << 2) + (lane >> 4)) ^ (arow & 7);
        bf16x8 af = *(bf16x8*)(sAg + (arow << 7) + (aslt << 4));
#pragma unroll
        for (int nf = 0; nf < 2; ++nf) {
          int brow = (nf << 4) + (lane & 15);
          int bslt = ((ks << 2) + (lane >> 4)) ^ (brow & 7);
          bf16x8 bfr = *(bf16x8*)(sBg + (brow << 7) + (bslt << 4));
          pacc[nf] = __builtin_amdgcn_mfma_f32_16x16x32_bf16(af, bfr, pacc[nf],
                                                             0, 0, 0);
        }
      }
      PIPE_BARRIER();
    }
    // group 1 -> LDS; group 0 (same (lw,lane) coords) adds + writes s_off
    if (grp == 1) {
#pragma unroll
      for (int nf = 0; nf < 2; ++nf)
#pragma unroll
        for (int r = 0; r < 4; ++r) s_red[gtid * 8 + nf * 4 + r] = pacc[nf][r];
    }
    __syncthreads();
    if (grp == 0) {
#pragma unroll
      for (int nf = 0; nf < 2; ++nf) {
#pragma unroll
        for (int r = 0; r < 4; ++r)
          pacc[nf][r] += s_red[gtid * 8 + nf * 4 + r];
        int o = (nf << 4) + (lane & 15);
        int px0 = (lw << 4) + ((lane >> 4) << 2);
        if (o < 18) {
          float bo = ob[o];
          *(float4*)(s_off + o * 64 + px0) =
              make_float4(pacc[nf][0] + bo, pacc[nf][1] + bo, pacc[nf][2] + bo,
                          pacc[nf][3] + bo);
        } else if (o < 27) {
          float bm = mb[o - 18];
          float4 v;
          v.x = 2.f / (1.f + expf(-(pacc[nf][0] + bm)));
          v.y = 2.f / (1.f + expf(-(pacc[nf][1] + bm)));
          v.z = 2.f / (1.f + expf(-(pacc[nf][2] + bm)));
          v.w = 2.f / (1.f + expf(-(pacc[nf][3] + bm)));
          *(float4*)(s_off + o * 64 + px0) = v;
        }
      }
    }
    __syncthreads();
  }

  // ---- phase-1 corner tables (R12-exact math; source = s_off) ----
  for (int i = tid; i < 576; i += 512) {
    int k = i >> 6, pxi = i & 63;
    float dy = s_off[(2 * k) * 64 + pxi];
    float dx = s_off[(2 * k + 1) * 64 + pxi];
    float m = s_off[(18 + k) * 64 + pxi];
    float py = (float)(h - 1 + k / 3) + dy;
    float pxf = (float)(pxi - 1 + k % 3) + dx;
    float y0f = floorf(py), x0f = floorf(pxf);
    float wy = py - y0f, wx = pxf - x0f;
    int y0 = (int)y0f, x0 = (int)x0f;
    int y1 = y0 + 1, x1 = x0 + 1;
    float w00 = (1.f - wy) * (1.f - wx) * m;
    float w01 = (1.f - wy) * wx * m;
    float w10 = wy * (1.f - wx) * m;
    float w11 = wy * wx * m;
    bool vy0 = ((unsigned)y0 < 64u), vy1 = ((unsigned)y1 < 64u);
    bool vx0 = ((unsigned)x0 < 64u), vx1 = ((unsigned)x1 < 64u);
    if (!(vy0 && vx0)) w00 = 0.f;
    if (!(vy0 && vx1)) w01 = 0.f;
    if (!(vy1 && vx0)) w10 = 0.f;
    if (!(vy1 && vx1)) w11 = 0.f;
    int y0c = min(max(y0, 0), 63), y1c = min(max(y1, 0), 63);
    int x0c = min(max(x0, 0), 63), x1c = min(max(x1, 0), 63);
    int xp = min(max(x0, 0), 62);
    int s0 = x0c - xp, s1 = x1c - xp;
    float a0 = (s0 ? 0.f : w00) + (s1 ? 0.f : w01);
    float b0 = (s0 ? w00 : 0.f) + (s1 ? w01 : 0.f);
    float a1 = (s0 ? 0.f : w10) + (s1 ? 0.f : w11);
    float b1 = (s0 ? w10 : 0.f) + (s1 ? w11 : 0.f);
    s_cw[i] = make_uint2(pk2(a0, b0), pk2(a1, b1));
    s_ci[i] = make_ushort2((unsigned short)(y0c * 64 + xp),
                           (unsigned short)(y1c * 64 + xp));
  }
  __syncthreads();

  // ===================== PHASE 1: main GEMM (R12-exact) ===================
  f32x4 acc[4][2];
#pragma unroll
  for (int mf = 0; mf < 4; ++mf)
#pragma unroll
    for (int nf = 0; nf < 2; ++nf) acc[mf][nf] = (f32x4){0.f, 0.f, 0.f, 0.f};

  const int aslot = (lane << 7) + ((wv ^ (lane & 7)) << 4);

  unsigned rxu[16];
  float4 cwC;
  {
    uint2 p = s_cw[lane];
    cwC.x = __uint_as_float(p.x << 16);
    cwC.y = __uint_as_float(p.x & 0xffff0000u);
    cwC.z = __uint_as_float(p.y << 16);
    cwC.w = __uint_as_float(p.y & 0xffff0000u);
    ushort2 ci0 = s_ci[lane];
    const char* xcn = xbh + (((wv << 3) * HWN) << 1);
#pragma unroll
    for (int s = 0; s < 8; ++s) {
      const char* xc = xcn + ((s * HWN) << 1);
      __builtin_memcpy(&rxu[2 * s + 0], xc + ((int)ci0.x << 1), 4);
      __builtin_memcpy(&rxu[2 * s + 1], xc + ((int)ci0.y << 1), 4);
    }
  }

#pragma unroll 1
  for (int t = 0; t < 36; ++t) {
    const int cq = t / 9;
    const int tap = t - cq * 9;
    {
      unsigned pkv[4];
#pragma unroll
      for (int j2 = 0; j2 < 4; ++j2) {
        float vv[2];
#pragma unroll
        for (int u = 0; u < 2; ++u) {
          unsigned d0 = rxu[4 * j2 + 2 * u], d1 = rxu[4 * j2 + 2 * u + 1];
          float v = cwC.x * __uint_as_float(d0 << 16);
          v = fmaf(cwC.y, __uint_as_float(d0 & 0xffff0000u), v);
          v = fmaf(cwC.z, __uint_as_float(d1 << 16), v);
          vv[u] = fmaf(cwC.w, __uint_as_float(d1 & 0xffff0000u), v);
        }
        pkv[j2] = pk2(vv[0], vv[1]);
      }
      *(uint4*)(sA + aslot) = make_uint4(pkv[0], pkv[1], pkv[2], pkv[3]);
    }
    {
      const unsigned short* wp = wT + (tap << 16) + (cq << 6);
#pragma unroll
      for (int r = 0; r < 4; ++r) {
        int idx = (r << 9) + tid;
        int o = idx >> 3, seg = idx & 7;
        uint4 v = *(const uint4*)(wp + (o << 8) + (seg << 3));
        int slot = seg ^ (o & 7);
        *(uint4*)(sB + (o << 7) + (slot << 4)) = v;
      }
    }
    {
      const int tn = t < 35 ? t + 1 : 35;
      const int cqn = tn / 9;
      const int tapn = tn - cqn * 9;
      uint2 p = s_cw[(tapn << 6) + lane];
      float4 cwN;
      cwN.x = __uint_as_float(p.x << 16);
      cwN.y = __uint_as_float(p.x & 0xffff0000u);
      cwN.z = __uint_as_float(p.y << 16);
      cwN.w = __uint_as_float(p.y & 0xffff0000u);
      ushort2 ciN = s_ci[(tapn << 6) + lane];
      const char* xcn = xbh + ((((cqn << 3) + wv) << 3) * HWN << 1);
#pragma unroll
      for (int s = 0; s < 8; ++s) {
        const char* xc = xcn + ((s * HWN) << 1);
        __builtin_memcpy(&rxu[2 * s + 0], xc + ((int)ciN.x << 1), 4);
        __builtin_memcpy(&rxu[2 * s + 1], xc + ((int)ciN.y << 1), 4);
      }
      cwC = cwN;
    }
    PIPE_BARRIER();
#pragma unroll
    for (int ks = 0; ks < 2; ++ks) {
      bf16x8 af[4], bfr[2];
#pragma unroll
      for (int mf = 0; mf < 4; ++mf) {
        int row = (mf << 4) + (lane & 15);
        int slot = ((ks << 2) + (lane >> 4)) ^ (row & 7);
        af[mf] = *(bf16x8*)(sA + (row << 7) + (slot << 4));
      }
#pragma unroll
      for (int nf = 0; nf < 2; ++nf) {
        int row = (wv << 5) + (nf << 4) + (lane & 15);
        int slot = ((ks << 2) + (lane >> 4)) ^ (row & 7);
        bfr[nf] = *(bf16x8*)(sB + (row << 7) + (slot << 4));
      }
#pragma unroll
      for (int mf = 0; mf < 4; ++mf)
#pragma unroll
        for (int nf = 0; nf < 2; ++nf)
          acc[mf][nf] = __builtin_amdgcn_mfma_f32_16x16x32_bf16(
              af[mf], bfr[nf], acc[mf][nf], 0, 0, 0);
    }
    PIPE_BARRIER();
  }

  // ---- BN partial stats ----
#pragma unroll
  for (int nf = 0; nf < 2; ++nf) {
    float s = 0.f, q = 0.f;
#pragma unroll
    for (int mf = 0; mf < 4; ++mf)
#pragma unroll
      for (int r = 0; r < 4; ++r) {
        float v = acc[mf][nf][r];
        s += v;
        q = fmaf(v, v, q);
      }
    s += __shfl_down(s, 32);
    q += __shfl_down(q, 32);
    s += __shfl_down(s, 16);
    q += __shfl_down(q, 16);
    if (lane < 16) {
      int o = (wv << 5) + (nf << 4) + lane;
      psum[(o << 9) + mblk] = s;
      psq[(o << 9) + mblk] = q;
    }
  }

  // ---- store via LDS transpose, 2 passes of 128 o-rows (raw, no BN) ----
  __syncthreads();
  for (int p = 0; p < 2; ++p) {
    if ((wv >> 2) == p) {
#pragma unroll
      for (int mf = 0; mf < 4; ++mf)
#pragma unroll
        for (int nf = 0; nf < 2; ++nf) {
          int ro = ((wv & 3) << 5) + (nf << 4) + (lane & 15);
#pragma unroll
          for (int r = 0; r < 4; ++r)
            tr[ro * 65 + (mf << 4) + ((lane >> 4) << 2) + r] = acc[mf][nf][r];
        }
    }
    __syncthreads();
#pragma unroll
    for (int it = 0; it < 4; ++it) {
      int idx = tid + (it << 9);
      int ro = idx >> 4, qd = idx & 15;
      float4 v = make_float4(tr[ro * 65 + qd * 4], tr[ro * 65 + qd * 4 + 1],
                             tr[ro * 65 + qd * 4 + 2], tr[ro * 65 + qd * 4 + 3]);
      *(float4*)(out + (((b << 8) + (p << 7) + ro) << 12) + (h << 6) +
                 (qd << 2)) = v;
    }
    __syncthreads();
  }
}

// ===========================================================================
// Fallback path (ws too small): f32 end to end.
// ===========================================================================
__global__ __launch_bounds__(256) void k_wprep(const float* __restrict__ wgt,
                                               unsigned short* __restrict__ wT) {
  const int o = blockIdx.x, c = threadIdx.x;
  const float* wp = wgt + o * 2304 + c * 9;
  float v[9];
#pragma unroll
  for (int t = 0; t < 9; ++t) v[t] = wp[t];
#pragma unroll
  for (int t = 0; t < 9; ++t) {
    unsigned u = __float_as_uint(v[t]);
    u += 0x7fff + ((u >> 16) & 1);
    wT[(t << 16) + (o << 8) + c] = (unsigned short)(u >> 16);
  }
}

__global__ __launch_bounds__(512, 4) void k_offmod_fb(
    const float* __restrict__ x, const float* __restrict__ ow,
    const float* __restrict__ ob, const float* __restrict__ mw,
    const float* __restrict__ mb, float* __restrict__ dyb,
    float* __restrict__ dxb, float* __restrict__ mskb) {
  __shared__ float ps[13824];
  const int tid = threadIdx.x;
  const int bid = blockIdx.x;
  const int b = bid & 7;
  const int h = bid >> 3;
  const int cg = __builtin_amdgcn_readfirstlane(tid >> 6);
  const int px = tid & 63;
  float acc[27];
#pragma unroll
  for (int i = 0; i < 27; ++i) acc[i] = 0.f;

  const float* xb = x + b * (CI * HWN);
  const int h0c = max(h - 1, 0), h2c = min(h + 1, 63);
  const bool v0 = h > 0, v2 = h < 63;
  const bool e0 = (px == 0), e63 = (px == 63);
  const float* xw = xb + (cg << 5) * HWN;

#pragma unroll 1
  for (int i = 0; i < 32; ++i) {
    const float* xc = xw + i * HWN;
    float c0 = xc[h0c * 64 + px];
    float c1 = xc[h * 64 + px];
    float c2 = xc[h2c * 64 + px];
    c0 = v0 ? c0 : 0.f;
    c2 = v2 ? c2 : 0.f;
    float l0 = __shfl_up(c0, 1), l1 = __shfl_up(c1, 1), l2 = __shfl_up(c2, 1);
    float r0 = __shfl_down(c0, 1), r1 = __shfl_down(c1, 1),
          r2 = __shfl_down(c2, 1);
    l0 = e0 ? 0.f : l0;
    l1 = e0 ? 0.f : l1;
    l2 = e0 ? 0.f : l2;
    r0 = e63 ? 0.f : r0;
    r1 = e63 ? 0.f : r1;
    r2 = e63 ? 0.f : r2;
    float xv[9] = {l0, c0, r0, l1, c1, r1, l2, c2, r2};
    const int c = (cg << 5) + i;
    const float* owp = ow + c * 9;
    const float* mwp = mw + c * 9;
#pragma unroll
    for (int ch = 0; ch < 18; ++ch)
#pragma unroll
      for (int k = 0; k < 9; ++k)
        acc[ch] = fmaf(owp[ch * 2304 + k], xv[k], acc[ch]);
#pragma unroll
    for (int ch = 0; ch < 9; ++ch)
#pragma unroll
      for (int k = 0; k < 9; ++k)
        acc[18 + ch] = fmaf(mwp[ch * 2304 + k], xv[k], acc[18 + ch]);
  }

#pragma unroll
  for (int ch = 0; ch < 27; ++ch) ps[(px * 27 + ch) * 8 + cg] = acc[ch];
  __syncthreads();
  for (int i = tid; i < 1728; i += 512) {
    int p2 = i / 27;
    int ch = i - p2 * 27;
    float s = 0.f;
#pragma unroll
    for (int g = 0; g < 8; ++g) s += ps[i * 8 + g];
    if (ch < 18) {
      s += ob[ch];
      int k = ch >> 1;
      int o9 = ((b * 9 + k) << 12) + (h << 6) + p2;
      if ((ch & 1) == 0) dyb[o9] = s;
      else dxb[o9] = s;
    } else {
      int k = ch - 18;
      s += mb[k];
      mskb[((b * 9 + k) << 12) + (h << 6) + p2] = 2.f / (1.f + expf(-s));
    }
  }
}

__global__ __launch_bounds__(512, 4) void k_main_f32(
    const float* __restrict__ x, const unsigned short* __restrict__ wT,
    const float* __restrict__ dyb, const float* __restrict__ dxb,
    const float* __restrict__ mskb, float* __restrict__ out,
    float* __restrict__ psum, float* __restrict__ psq) {
  __shared__ __align__(16) char smem[50176];
  uint2* s_cw = (uint2*)smem;
  ushort4* s_ci = (ushort4*)(smem + 4608);
  char* sA = smem + 9216;
  char* sB = smem + 17408;
  float* tr = (float*)(smem + 9216);

  const int tid = threadIdx.x;
  const int mblk = blockIdx.x;
  const int b = mblk >> 6, h = mblk & 63;
  const int lane = tid & 63;
  const int wv = tid >> 6;

  for (int i = tid; i < 576; i += 512) {
    int k = i >> 6, pxi = i & 63;
    int o9 = ((b * 9 + k) << 12) + (h << 6) + pxi;
    float m = mskb[o9];
    float py = (float)(h - 1 + k / 3) + dyb[o9];
    float pxf = (float)(pxi - 1 + k % 3) + dxb[o9];
    float y0f = floorf(py), x0f = floorf(pxf);
    float wy = py - y0f, wx = pxf - x0f;
    int y0 = (int)y0f, x0 = (int)x0f;
    int y1 = y0 + 1, x1 = x0 + 1;
    float w00 = (1.f - wy) * (1.f - wx) * m;
    float w01 = (1.f - wy) * wx * m;
    float w10 = wy * (1.f - wx) * m;
    float w11 = wy * wx * m;
    bool vy0 = ((unsigned)y0 < 64u), vy1 = ((unsigned)y1 < 64u);
    bool vx0 = ((unsigned)x0 < 64u), vx1 = ((unsigned)x1 < 64u);
    if (!(vy0 && vx0)) w00 = 0.f;
    if (!(vy0 && vx1)) w01 = 0.f;
    if (!(vy1 && vx0)) w10 = 0.f;
    if (!(vy1 && vx1)) w11 = 0.f;
    int y0c = min(max(y0, 0), 63), y1c = min(max(y1, 0), 63);
    int x0c = min(max(x0, 0), 63), x1c = min(max(x1, 0), 63);
    s_cw[i] = make_uint2(pk2(w00, w01), pk2(w10, w11));
    s_ci[i] = make_ushort4((unsigned short)(y0c * 64 + x0c),
                           (unsigned short)(y0c * 64 + x1c),
                           (unsigned short)(y1c * 64 + x0c),
                           (unsigned short)(y1c * 64 + x1c));
  }
  __syncthreads();

  f32x4 acc[4][2];
#pragma unroll
  for (int mf = 0; mf < 4; ++mf)
#pragma unroll
    for (int nf = 0; nf < 2; ++nf) acc[mf][nf] = (f32x4){0.f, 0.f, 0.f, 0.f};

  const float* xb = x + b * (CI * HWN);
  const int aslot = (lane << 7) + ((wv ^ (lane & 7)) << 4);

  float rx[32];
  float4 cwC;
  {
    uint2 p = s_cw[lane];
    cwC.x = __uint_as_float(p.x << 16);
    cwC.y = __uint_as_float(p.x & 0xffff0000u);
    cwC.z = __uint_as_float(p.y << 16);
    cwC.w = __uint_as_float(p.y & 0xffff0000u);
    ushort4 ci0 = s_ci[lane];
    const float* xpn = xb + (wv << 3) * HWN;
#pragma unroll
    for (int s = 0; s < 8; ++s) {
      const float* xp = xpn + s * HWN;
      rx[4 * s + 0] = xp[ci0.x];
      rx[4 * s + 1] = xp[ci0.y];
      rx[4 * s + 2] = xp[ci0.z];
      rx[4 * s + 3] = xp[ci0.w];
    }
  }

#pragma unroll 1
  for (int t = 0; t < 36; ++t) {
    const int cq = t / 9;
    const int tap = t - cq * 9;
    {
      unsigned pkv[4];
#pragma unroll
      for (int j2 = 0; j2 < 4; ++j2) {
        float v0 = cwC.x * rx[8 * j2 + 0];
        v0 = fmaf(cwC.y, rx[8 * j2 + 1], v0);
        v0 = fmaf(cwC.z, rx[8 * j2 + 2], v0);
        v0 = fmaf(cwC.w, rx[8 * j2 + 3], v0);
        float v1 = cwC.x * rx[8 * j2 + 4];
        v1 = fmaf(cwC.y, rx[8 * j2 + 5], v1);
        v1 = fmaf(cwC.z, rx[8 * j2 + 6], v1);
        v1 = fmaf(cwC.w, rx[8 * j2 + 7], v1);
        pkv[j2] = pk2(v0, v1);
      }
      *(uint4*)(sA + aslot) = make_uint4(pkv[0], pkv[1], pkv[2], pkv[3]);
    }
    {
      const unsigned short* wp = wT + (tap << 16) + (cq << 6);
#pragma unroll
      for (int r = 0; r < 4; ++r) {
        int idx = (r << 9) + tid;
        int o = idx >> 3, seg = idx & 7;
        uint4 v = *(const uint4*)(wp + (o << 8) + (seg << 3));
        int slot = seg ^ (o & 7);
        *(uint4*)(sB + (o << 7) + (slot << 4)) = v;
      }
    }
    {
      const int tn = t < 35 ? t + 1 : 35;
      const int cqn = tn / 9;
      const int tapn = tn - cqn * 9;
      uint2 p = s_cw[(tapn << 6) + lane];
      float4 cwN;
      cwN.x = __uint_as_float(p.x << 16);
      cwN.y = __uint_as_float(p.x & 0xffff0000u);
      cwN.z = __uint_as_float(p.y << 16);
      cwN.w = __uint_as_float(p.y & 0xffff0000u);
      ushort4 ciN = s_ci[(tapn << 6) + lane];
      const float* xpn = xb + (((cqn << 3) + wv) << 3) * HWN;
#pragma unroll
      for (int s = 0; s < 8; ++s) {
        const float* xp = xpn + s * HWN;
        rx[4 * s + 0] = xp[ciN.x];
        rx[4 * s + 1] = xp[ciN.y];
        rx[4 * s + 2] = xp[ciN.z];
        rx[4 * s + 3] = xp[ciN.w];
      }
      cwC = cwN;
    }
    PIPE_BARRIER();
#pragma unroll
    for (int ks = 0; ks < 2; ++ks) {
      bf16x8 af[4], bfr[2];
#pragma unroll
      for (int mf = 0; mf < 4; ++mf) {
        int row = (mf << 4) + (lane & 15);
        int slot = ((ks << 2) + (lane >> 4)) ^ (row & 7);
        af[mf] = *(bf16x8*)(sA + (row << 7) + (slot << 4));
      }
#pragma unroll
      for (int nf = 0; nf < 2; ++nf) {
        int row = (wv << 5) + (nf << 4) + (lane & 15);
        int slot = ((ks << 2) + (lane >> 4)) ^ (row & 7);
        bfr[nf] = *(bf16x8*)(sB + (row << 7) + (slot << 4));
      }
#pragma unroll
      for (int mf = 0; mf < 4; ++mf)
#pragma unroll
        for (int nf = 0; nf < 2; ++nf)
          acc[mf][nf] = __builtin_amdgcn_mfma_f32_16x16x32_bf16(
              af[mf], bfr[nf], acc[mf][nf], 0, 0, 0);
    }
    PIPE_BARRIER();
  }

#pragma unroll
  for (int nf = 0; nf < 2; ++nf) {
    float s = 0.f, q = 0.f;
#pragma unroll
    for (int mf = 0; mf < 4; ++mf)
#pragma unroll
      for (int r = 0; r < 4; ++r) {
        float v = acc[mf][nf][r];
        s += v;
        q = fmaf(v, v, q);
      }
    s += __shfl_down(s, 32);
    q += __shfl_down(q, 32);
    s += __shfl_down(s, 16);
    q += __shfl_down(q, 16);
    if (lane < 16) {
      int o = (wv << 5) + (nf << 4) + lane;
      psum[(o << 9) + mblk] = s;
      psq[(o << 9) + mblk] = q;
    }
  }

  __syncthreads();
  for (int p = 0; p < 2; ++p) {
    if ((wv >> 2) == p) {
#pragma unroll
      for (int mf = 0; mf < 4; ++mf)
#pragma unroll
        for (int nf = 0; nf < 2; ++nf) {
          int ro = ((wv & 3) << 5) + (nf << 4) + (lane & 15);
#pragma unroll
          for (int r = 0; r < 4; ++r)
            tr[ro * 65 + (mf << 4) + ((lane >> 4) << 2) + r] = acc[mf][nf][r];
        }
    }
    __syncthreads();
#pragma unroll
    for (int it = 0; it < 4; ++it) {
      int idx = tid + (it << 9);
      int ro = idx >> 4, qd = idx & 15;
      float4 v = make_float4(tr[ro * 65 + qd * 4], tr[ro * 65 + qd * 4 + 1],
                             tr[ro * 65 + qd * 4 + 2], tr[ro * 65 + qd * 4 + 3]);
      *(float4*)(out + (((b << 8) + (p << 7) + ro) << 12) + (h << 6) +
                 (qd << 2)) = v;
    }
    __syncthreads();
  }
}

__global__ __launch_bounds__(64) void k_stats(
    const float* __restrict__ psum, const float* __restrict__ psq,
    const float* __restrict__ gamma, const float* __restrict__ beta,
    float* __restrict__ scale, float* __restrict__ shift) {
  const int o = blockIdx.x;
  const int t = threadIdx.x;
  float s = 0.f, q = 0.f;
#pragma unroll
  for (int i = 0; i < 8; ++i) {
    s += psum[(o << 9) + t + (i << 6)];
    q += psq[(o << 9) + t + (i << 6)];
  }
#pragma unroll
  for (int off = 32; off > 0; off >>= 1) {
    s += __shfl_down(s, off, 64);
    q += __shfl_down(q, off, 64);
  }
  if (t == 0) {
    const float inv_n = 1.f / 32768.f;
    float mean = s * inv_n;
    float var = fmaf(-mean, mean, q * inv_n);
    float sc = gamma[o] * rsqrtf(var + 1e-5f);
    scale[o] = sc;
    shift[o] = fmaf(-mean, sc, beta[o]);
  }
}

__global__ __launch_bounds__(256) void k_bnrelu(
    float* __restrict__ out, const float* __restrict__ scale,
    const float* __restrict__ shift) {
  int idx = blockIdx.x * 256 + threadIdx.x;
  int o = (idx >> 10) & 255;
  float sc = scale[o], sh = shift[o];
  float4 v = ((float4*)out)[idx];
  v.x = fmaxf(fmaf(v.x, sc, sh), 0.f);
  v.y = fmaxf(fmaf(v.y, sc, sh), 0.f);
  v.z = fmaxf(fmaf(v.z, sc, sh), 0.f);
  v.w = fmaxf(fmaf(v.w, sc, sh), 0.f);
  ((float4*)out)[idx] = v;
}

extern "C" void kernel_launch(void* const* d_in, const int* in_sizes, int n_in,
                              void* d_out, int out_size, void* d_ws,
                              size_t ws_size, hipStream_t stream) {
  const float* x = (const float*)d_in[0];
  const float* ow = (const float*)d_in[1];
  const float* ob = (const float*)d_in[2];
  const float* mw = (const float*)d_in[3];
  const float* mb = (const float*)d_in[4];
  const float* wgt = (const float*)d_in[5];
  // d_in[6] = conv bias: cancels exactly in BN (out - mean(out)), skipped.
  const float* gamma = (const float*)d_in[7];
  const float* beta = (const float*)d_in[8];
  float* out = (float*)d_out;

  float* ws = (float*)d_ws;
  float* dyb = ws;                  // 294912 (fallback only)
  float* dxb = dyb + 294912;        // 294912 (fallback only)
  float* mskb = dxb + 294912;       // 294912 (fallback only)
  float* psum = mskb + 294912;      // 131072
  float* psq = psum + 131072;       // 131072
  float* scale = psq + 131072;      // 256
  float* shift = scale + 256;       // 256
  unsigned short* wT = (unsigned short*)(shift + 256);  // 9*256*256 bf16
  unsigned short* xhp = wT + 589824;                    // 8.39M bf16
  unsigned short* wTo = xhp + 8388608;                  // 9*32*256 bf16
  const size_t WS_NEED = (size_t)(294912 * 3 + 131072 * 2 + 512) * 4 +
                         589824 * 2 + 8388608 * 2 + 73728 * 2;

  if (ws_size >= WS_NEED) {
    k_prep<<<4384, 256, 0, stream>>>(x, wgt, ow, mw, wT, wTo, xhp);
    k_fused2<<<512, 512, 0, stream>>>(xhp, wT, wTo, ob, mb, out, psum, psq);
  } else {
    k_wprep<<<256, 256, 0, stream>>>(wgt, wT);
    k_offmod_fb<<<512, 512, 0, stream>>>(x, ow, ob, mw, mb, dyb, dxb, mskb);
    k_main_f32<<<512, 512, 0, stream>>>(x, wT, dyb, dxb, mskb, out, psum, psq);
  }
  k_stats<<<256, 64, 0, stream>>>(psum, psq, gamma, beta, scale, shift);
  k_bnrelu<<<8192, 256, 0, stream>>>(out, scale, shift);
}

// Round 17
// 182.509 us; speedup vs baseline: 1.6828x; 1.6828x over previous
//
#include <hip/hip_runtime.h>
#include <math.h>

#define CI 256
#define CO 256
#define HWN 4096  // H*W

typedef short bf16x8 __attribute__((ext_vector_type(8)));
typedef float f32x4 __attribute__((ext_vector_type(4)));

__device__ inline unsigned pk2(float a, float b) {  // RNE pack 2 f32 -> 2 bf16
  unsigned ua = __float_as_uint(a), ub = __float_as_uint(b);
  ua += 0x7fff + ((ua >> 16) & 1);
  ub += 0x7fff + ((ub >> 16) & 1);
  return (ua >> 16) | (ub & 0xffff0000u);
}

// Raw barrier that does NOT drain vmcnt (keeps prefetch loads in flight).
#define PIPE_BARRIER()                                    \
  do {                                                    \
    __builtin_amdgcn_sched_barrier(0);                    \
    asm volatile("s_waitcnt lgkmcnt(0)" ::: "memory");    \
    __builtin_amdgcn_s_barrier();                         \
    __builtin_amdgcn_sched_barrier(0);                    \
  } while (0)

// ---------------------------------------------------------------------------
// Kernel 0: fused prep. bid<4096: x f32->bf16; 4096..4351: wT; 4352..4383: wTo.
// ---------------------------------------------------------------------------
__global__ __launch_bounds__(256) void k_prep(
    const float* __restrict__ x, const float* __restrict__ wgt,
    const float* __restrict__ ow, const float* __restrict__ mw,
    unsigned short* __restrict__ wT, unsigned short* __restrict__ wTo,
    unsigned short* __restrict__ xhp) {
  const int bid = blockIdx.x, tid = threadIdx.x;
  if (bid < 4096) {
    int i = bid * 256 + tid;
    const float4* xf = (const float4*)x;
    float4 a = xf[2 * i], b = xf[2 * i + 1];
    ((uint4*)xhp)[i] = make_uint4(pk2(a.x, a.y), pk2(a.z, a.w), pk2(b.x, b.y),
                                  pk2(b.z, b.w));
  } else if (bid < 4352) {
    int o = bid - 4096, c = tid;
    const float* wp = wgt + o * 2304 + c * 9;
    float v[9];
#pragma unroll
    for (int t = 0; t < 9; ++t) v[t] = wp[t];
#pragma unroll
    for (int t = 0; t < 9; ++t) {
      unsigned u = __float_as_uint(v[t]);
      u += 0x7fff + ((u >> 16) & 1);
      wT[(t << 16) + (o << 8) + c] = (unsigned short)(u >> 16);
    }
  } else {
    int o = bid - 4352, c = tid;
    float v[9];
    if (o < 18) {
      const float* wp = ow + o * 2304 + c * 9;
#pragma unroll
      for (int t = 0; t < 9; ++t) v[t] = wp[t];
    } else if (o < 27) {
      const float* wp = mw + (o - 18) * 2304 + c * 9;
#pragma unroll
      for (int t = 0; t < 9; ++t) v[t] = wp[t];
    } else {
#pragma unroll
      for (int t = 0; t < 9; ++t) v[t] = 0.f;
    }
#pragma unroll
    for (int t = 0; t < 9; ++t) {
      unsigned u = __float_as_uint(v[t]);
      u += 0x7fff + ((u >> 16) & 1);
      wTo[(t << 13) + (o << 8) + c] = (unsigned short)(u >> 16);
    }
  }
}

// ---------------------------------------------------------------------------
// FUSED kernel (R15-exact, launch_bounds(512,4) — the L2-optimal 2 blocks/CU;
// (512,6) was tried in R16: occupancy rose but L2 working set tripled ->
// FETCH 92->520 MB -> HBM-bound regression 172->300 us).
// Phase 0 = offset conv in-LDS; phase 1 = R12-exact main gather-GEMM.
// ---------------------------------------------------------------------------
__global__ __launch_bounds__(512, 4) void k_fused2(
    const unsigned short* __restrict__ xh, const unsigned short* __restrict__ wT,
    const unsigned short* __restrict__ wTo, const float* __restrict__ ob,
    const float* __restrict__ mb, float* __restrict__ out,
    float* __restrict__ psum, float* __restrict__ psq) {
  __shared__ __align__(16) char smem[47872];
  uint2* s_cw = (uint2*)smem;               // [9][64] phase-1 corner w
  ushort2* s_ci = (ushort2*)(smem + 4608);  // [9][64] phase-1 pair bases
  char* sA = smem + 6912;                   // phase-1 A (8 KB)
  char* sB = smem + 15104;                  // phase-1 B (32 KB)
  float* tr = (float*)(smem + 6912);        // store-transpose reuse
  char* sA0 = smem + 6912;                  // phase-0 group-0 A (8 KB)
  char* sA1 = smem + 15104;                 // phase-0 group-1 A (8 KB)
  char* sB0 = smem + 23296;                 // phase-0 group-0 B (4 KB)
  char* sB1 = smem + 27392;                 // phase-0 group-1 B (4 KB)
  float* s_red = (float*)(smem + 6912);     // phase-0 reduce (after loop)
  float* s_off = (float*)(smem + 31488);    // [27][64] offsets (6.9 KB)

  const int tid = threadIdx.x;
  const int mblk = blockIdx.x;  // b*64 + h
  const int b = mblk >> 6, h = mblk & 63;
  const int lane = tid & 63;
  const int wv = tid >> 6;
  const char* xbh = (const char*)(xh + (size_t)b * (CI * HWN));

  // ===================== PHASE 0: offset conv (27 ch) =====================
  {
    const int grp = wv >> 2;  // 0: cq 0-1, 1: cq 2-3
    const int lw = wv & 3;
    const int gtid = tid & 255;
    const int px = lane;
    char* sAg = grp ? sA1 : sA0;
    char* sBg = grp ? sB1 : sB0;
    f32x4 pacc[2];
    pacc[0] = (f32x4){0.f, 0.f, 0.f, 0.f};
    pacc[1] = (f32x4){0.f, 0.f, 0.f, 0.f};

    unsigned rxu[16];
    float cwA, cwB;
    {
      int y0 = h - 1, x0 = px - 1;
      float w = (((unsigned)y0 < 64u) && ((unsigned)x0 < 64u)) ? 1.f : 0.f;
      int y0c = min(max(y0, 0), 63);
      int xp = min(max(x0, 0), 62);
      int s0 = min(max(x0, 0), 63) - xp;
      cwA = s0 ? 0.f : w;
      cwB = s0 ? w : 0.f;
      int ci = y0c * 64 + xp;
#pragma unroll
      for (int g2 = 0; g2 < 2; ++g2) {
        int g = lw + (g2 << 2);
#pragma unroll
        for (int j = 0; j < 8; ++j) {
          int c = ((grp << 1) << 6) + (g << 3) + j;
          __builtin_memcpy(&rxu[(g2 << 3) + j], xbh + (((c << 12) + ci) << 1),
                           4);
        }
      }
    }

#pragma unroll 1
    for (int t = 0; t < 18; ++t) {
      const int cqi = t / 9;
      const int tap = t - cqi * 9;
      const int cq = (grp << 1) + cqi;
#pragma unroll
      for (int g2 = 0; g2 < 2; ++g2) {
        unsigned pkv[4];
#pragma unroll
        for (int j2 = 0; j2 < 4; ++j2) {
          unsigned d0 = rxu[(g2 << 3) + (j2 << 1)];
          unsigned d1 = rxu[(g2 << 3) + (j2 << 1) + 1];
          float v0 = cwA * __uint_as_float(d0 << 16);
          v0 = fmaf(cwB, __uint_as_float(d0 & 0xffff0000u), v0);
          float v1 = cwA * __uint_as_float(d1 << 16);
          v1 = fmaf(cwB, __uint_as_float(d1 & 0xffff0000u), v1);
          pkv[j2] = pk2(v0, v1);
        }
        int g = lw + (g2 << 2);
        *(uint4*)(sAg + (px << 7) + ((g ^ (px & 7)) << 4)) =
            make_uint4(pkv[0], pkv[1], pkv[2], pkv[3]);
      }
      {
        int o = gtid >> 3, seg = gtid & 7;
        uint4 v = *(const uint4*)(wTo + (tap << 13) + (o << 8) + (cq << 6) +
                                  (seg << 3));
        *(uint4*)(sBg + (o << 7) + ((seg ^ (o & 7)) << 4)) = v;
      }
      {
        const int tn = t < 17 ? t + 1 : 17;
        const int cqni = tn / 9;
        const int tapn = tn - cqni * 9;
        const int cqn = (grp << 1) + cqni;
        int ky = tapn / 3, kx = tapn - 3 * ky;
        int y0 = h - 1 + ky, x0 = px - 1 + kx;
        float w = (((unsigned)y0 < 64u) && ((unsigned)x0 < 64u)) ? 1.f : 0.f;
        int y0c = min(max(y0, 0), 63);
        int xp = min(max(x0, 0), 62);
        int s0 = min(max(x0, 0), 63) - xp;
        float cwAn = s0 ? 0.f : w;
        float cwBn = s0 ? w : 0.f;
        int ci = y0c * 64 + xp;
#pragma unroll
        for (int g2 = 0; g2 < 2; ++g2) {
          int g = lw + (g2 << 2);
#pragma unroll
          for (int j = 0; j < 8; ++j) {
            int c = (cqn << 6) + (g << 3) + j;
            __builtin_memcpy(&rxu[(g2 << 3) + j],
                             xbh + (((c << 12) + ci) << 1), 4);
          }
        }
        cwA = cwAn;
        cwB = cwBn;
      }
      PIPE_BARRIER();
#pragma unroll
      for (int ks = 0; ks < 2; ++ks) {
        int arow = (lw << 4) + (lane & 15);
        int aslt = ((ks << 2) + (lane >> 4)) ^ (arow & 7);
        bf16x8 af = *(bf16x8*)(sAg + (arow << 7) + (aslt << 4));
#pragma unroll
        for (int nf = 0; nf < 2; ++nf) {
          int brow = (nf << 4) + (lane & 15);
          int bslt = ((ks << 2) + (lane >> 4)) ^ (brow & 7);
          bf16x8 bfr = *(bf16x8*)(sBg + (brow << 7) + (bslt << 4));
          pacc[nf] = __builtin_amdgcn_mfma_f32_16x16x32_bf16(af, bfr, pacc[nf],
                                                             0, 0, 0);
        }
      }
      PIPE_BARRIER();
    }
    // group 1 -> LDS; group 0 (same (lw,lane) coords) adds + writes s_off
    if (grp == 1) {
#pragma unroll
      for (int nf = 0; nf < 2; ++nf)
#pragma unroll
        for (int r = 0; r < 4; ++r) s_red[gtid * 8 + nf * 4 + r] = pacc[nf][r];
    }
    __syncthreads();
    if (grp == 0) {
#pragma unroll
      for (int nf = 0; nf < 2; ++nf) {
#pragma unroll
        for (int r = 0; r < 4; ++r)
          pacc[nf][r] += s_red[gtid * 8 + nf * 4 + r];
        int o = (nf << 4) + (lane & 15);
        int px0 = (lw << 4) + ((lane >> 4) << 2);
        if (o < 18) {
          float bo = ob[o];
          *(float4*)(s_off + o * 64 + px0) =
              make_float4(pacc[nf][0] + bo, pacc[nf][1] + bo, pacc[nf][2] + bo,
                          pacc[nf][3] + bo);
        } else if (o < 27) {
          float bm = mb[o - 18];
          float4 v;
          v.x = 2.f / (1.f + expf(-(pacc[nf][0] + bm)));
          v.y = 2.f / (1.f + expf(-(pacc[nf][1] + bm)));
          v.z = 2.f / (1.f + expf(-(pacc[nf][2] + bm)));
          v.w = 2.f / (1.f + expf(-(pacc[nf][3] + bm)));
          *(float4*)(s_off + o * 64 + px0) = v;
        }
      }
    }
    __syncthreads();
  }

  // ---- phase-1 corner tables (R12-exact math; source = s_off) ----
  for (int i = tid; i < 576; i += 512) {
    int k = i >> 6, pxi = i & 63;
    float dy = s_off[(2 * k) * 64 + pxi];
    float dx = s_off[(2 * k + 1) * 64 + pxi];
    float m = s_off[(18 + k) * 64 + pxi];
    float py = (float)(h - 1 + k / 3) + dy;
    float pxf = (float)(pxi - 1 + k % 3) + dx;
    float y0f = floorf(py), x0f = floorf(pxf);
    float wy = py - y0f, wx = pxf - x0f;
    int y0 = (int)y0f, x0 = (int)x0f;
    int y1 = y0 + 1, x1 = x0 + 1;
    float w00 = (1.f - wy) * (1.f - wx) * m;
    float w01 = (1.f - wy) * wx * m;
    float w10 = wy * (1.f - wx) * m;
    float w11 = wy * wx * m;
    bool vy0 = ((unsigned)y0 < 64u), vy1 = ((unsigned)y1 < 64u);
    bool vx0 = ((unsigned)x0 < 64u), vx1 = ((unsigned)x1 < 64u);
    if (!(vy0 && vx0)) w00 = 0.f;
    if (!(vy0 && vx1)) w01 = 0.f;
    if (!(vy1 && vx0)) w10 = 0.f;
    if (!(vy1 && vx1)) w11 = 0.f;
    int y0c = min(max(y0, 0), 63), y1c = min(max(y1, 0), 63);
    int x0c = min(max(x0, 0), 63), x1c = min(max(x1, 0), 63);
    int xp = min(max(x0, 0), 62);
    int s0 = x0c - xp, s1 = x1c - xp;
    float a0 = (s0 ? 0.f : w00) + (s1 ? 0.f : w01);
    float b0 = (s0 ? w00 : 0.f) + (s1 ? w01 : 0.f);
    float a1 = (s0 ? 0.f : w10) + (s1 ? 0.f : w11);
    float b1 = (s0 ? w10 : 0.f) + (s1 ? w11 : 0.f);
    s_cw[i] = make_uint2(pk2(a0, b0), pk2(a1, b1));
    s_ci[i] = make_ushort2((unsigned short)(y0c * 64 + xp),
                           (unsigned short)(y1c * 64 + xp));
  }
  __syncthreads();

  // ===================== PHASE 1: main GEMM (R12-exact) ===================
  f32x4 acc[4][2];
#pragma unroll
  for (int mf = 0; mf < 4; ++mf)
#pragma unroll
    for (int nf = 0; nf < 2; ++nf) acc[mf][nf] = (f32x4){0.f, 0.f, 0.f, 0.f};

  const int aslot = (lane << 7) + ((wv ^ (lane & 7)) << 4);

  unsigned rxu[16];
  float4 cwC;
  {
    uint2 p = s_cw[lane];
    cwC.x = __uint_as_float(p.x << 16);
    cwC.y = __uint_as_float(p.x & 0xffff0000u);
    cwC.z = __uint_as_float(p.y << 16);
    cwC.w = __uint_as_float(p.y & 0xffff0000u);
    ushort2 ci0 = s_ci[lane];
    const char* xcn = xbh + (((wv << 3) * HWN) << 1);
#pragma unroll
    for (int s = 0; s < 8; ++s) {
      const char* xc = xcn + ((s * HWN) << 1);
      __builtin_memcpy(&rxu[2 * s + 0], xc + ((int)ci0.x << 1), 4);
      __builtin_memcpy(&rxu[2 * s + 1], xc + ((int)ci0.y << 1), 4);
    }
  }

#pragma unroll 1
  for (int t = 0; t < 36; ++t) {
    const int cq = t / 9;
    const int tap = t - cq * 9;
    {
      unsigned pkv[4];
#pragma unroll
      for (int j2 = 0; j2 < 4; ++j2) {
        float vv[2];
#pragma unroll
        for (int u = 0; u < 2; ++u) {
          unsigned d0 = rxu[4 * j2 + 2 * u], d1 = rxu[4 * j2 + 2 * u + 1];
          float v = cwC.x * __uint_as_float(d0 << 16);
          v = fmaf(cwC.y, __uint_as_float(d0 & 0xffff0000u), v);
          v = fmaf(cwC.z, __uint_as_float(d1 << 16), v);
          vv[u] = fmaf(cwC.w, __uint_as_float(d1 & 0xffff0000u), v);
        }
        pkv[j2] = pk2(vv[0], vv[1]);
      }
      *(uint4*)(sA + aslot) = make_uint4(pkv[0], pkv[1], pkv[2], pkv[3]);
    }
    {
      const unsigned short* wp = wT + (tap << 16) + (cq << 6);
#pragma unroll
      for (int r = 0; r < 4; ++r) {
        int idx = (r << 9) + tid;
        int o = idx >> 3, seg = idx & 7;
        uint4 v = *(const uint4*)(wp + (o << 8) + (seg << 3));
        int slot = seg ^ (o & 7);
        *(uint4*)(sB + (o << 7) + (slot << 4)) = v;
      }
    }
    {
      const int tn = t < 35 ? t + 1 : 35;
      const int cqn = tn / 9;
      const int tapn = tn - cqn * 9;
      uint2 p = s_cw[(tapn << 6) + lane];
      float4 cwN;
      cwN.x = __uint_as_float(p.x << 16);
      cwN.y = __uint_as_float(p.x & 0xffff0000u);
      cwN.z = __uint_as_float(p.y << 16);
      cwN.w = __uint_as_float(p.y & 0xffff0000u);
      ushort2 ciN = s_ci[(tapn << 6) + lane];
      const char* xcn = xbh + ((((cqn << 3) + wv) << 3) * HWN << 1);
#pragma unroll
      for (int s = 0; s < 8; ++s) {
        const char* xc = xcn + ((s * HWN) << 1);
        __builtin_memcpy(&rxu[2 * s + 0], xc + ((int)ciN.x << 1), 4);
        __builtin_memcpy(&rxu[2 * s + 1], xc + ((int)ciN.y << 1), 4);
      }
      cwC = cwN;
    }
    PIPE_BARRIER();
#pragma unroll
    for (int ks = 0; ks < 2; ++ks) {
      bf16x8 af[4], bfr[2];
#pragma unroll
      for (int mf = 0; mf < 4; ++mf) {
        int row = (mf << 4) + (lane & 15);
        int slot = ((ks << 2) + (lane >> 4)) ^ (row & 7);
        af[mf] = *(bf16x8*)(sA + (row << 7) + (slot << 4));
      }
#pragma unroll
      for (int nf = 0; nf < 2; ++nf) {
        int row = (wv << 5) + (nf << 4) + (lane & 15);
        int slot = ((ks << 2) + (lane >> 4)) ^ (row & 7);
        bfr[nf] = *(bf16x8*)(sB + (row << 7) + (slot << 4));
      }
#pragma unroll
      for (int mf = 0; mf < 4; ++mf)
#pragma unroll
        for (int nf = 0; nf < 2; ++nf)
          acc[mf][nf] = __builtin_amdgcn_mfma_f32_16x16x32_bf16(
              af[mf], bfr[nf], acc[mf][nf], 0, 0, 0);
    }
    PIPE_BARRIER();
  }

  // ---- BN partial stats ----
#pragma unroll
  for (int nf = 0; nf < 2; ++nf) {
    float s = 0.f, q = 0.f;
#pragma unroll
    for (int mf = 0; mf < 4; ++mf)
#pragma unroll
      for (int r = 0; r < 4; ++r) {
        float v = acc[mf][nf][r];
        s += v;
        q = fmaf(v, v, q);
      }
    s += __shfl_down(s, 32);
    q += __shfl_down(q, 32);
    s += __shfl_down(s, 16);
    q += __shfl_down(q, 16);
    if (lane < 16) {
      int o = (wv << 5) + (nf << 4) + lane;
      psum[(o << 9) + mblk] = s;
      psq[(o << 9) + mblk] = q;
    }
  }

  // ---- store via LDS transpose, 2 passes of 128 o-rows (raw, no BN) ----
  __syncthreads();
  for (int p = 0; p < 2; ++p) {
    if ((wv >> 2) == p) {
#pragma unroll
      for (int mf = 0; mf < 4; ++mf)
#pragma unroll
        for (int nf = 0; nf < 2; ++nf) {
          int ro = ((wv & 3) << 5) + (nf << 4) + (lane & 15);
#pragma unroll
          for (int r = 0; r < 4; ++r)
            tr[ro * 65 + (mf << 4) + ((lane >> 4) << 2) + r] = acc[mf][nf][r];
        }
    }
    __syncthreads();
#pragma unroll
    for (int it = 0; it < 4; ++it) {
      int idx = tid + (it << 9);
      int ro = idx >> 4, qd = idx & 15;
      float4 v = make_float4(tr[ro * 65 + qd * 4], tr[ro * 65 + qd * 4 + 1],
                             tr[ro * 65 + qd * 4 + 2], tr[ro * 65 + qd * 4 + 3]);
      *(float4*)(out + (((b << 8) + (p << 7) + ro) << 12) + (h << 6) +
                 (qd << 2)) = v;
    }
    __syncthreads();
  }
}

// ===========================================================================
// Fallback path (ws too small): f32 end to end.
// ===========================================================================
__global__ __launch_bounds__(256) void k_wprep(const float* __restrict__ wgt,
                                               unsigned short* __restrict__ wT) {
  const int o = blockIdx.x, c = threadIdx.x;
  const float* wp = wgt + o * 2304 + c * 9;
  float v[9];
#pragma unroll
  for (int t = 0; t < 9; ++t) v[t] = wp[t];
#pragma unroll
  for (int t = 0; t < 9; ++t) {
    unsigned u = __float_as_uint(v[t]);
    u += 0x7fff + ((u >> 16) & 1);
    wT[(t << 16) + (o << 8) + c] = (unsigned short)(u >> 16);
  }
}

__global__ __launch_bounds__(512, 4) void k_offmod_fb(
    const float* __restrict__ x, const float* __restrict__ ow,
    const float* __restrict__ ob, const float* __restrict__ mw,
    const float* __restrict__ mb, float* __restrict__ dyb,
    float* __restrict__ dxb, float* __restrict__ mskb) {
  __shared__ float ps[13824];
  const int tid = threadIdx.x;
  const int bid = blockIdx.x;
  const int b = bid & 7;
  const int h = bid >> 3;
  const int cg = __builtin_amdgcn_readfirstlane(tid >> 6);
  const int px = tid & 63;
  float acc[27];
#pragma unroll
  for (int i = 0; i < 27; ++i) acc[i] = 0.f;

  const float* xb = x + b * (CI * HWN);
  const int h0c = max(h - 1, 0), h2c = min(h + 1, 63);
  const bool v0 = h > 0, v2 = h < 63;
  const bool e0 = (px == 0), e63 = (px == 63);
  const float* xw = xb + (cg << 5) * HWN;

#pragma unroll 1
  for (int i = 0; i < 32; ++i) {
    const float* xc = xw + i * HWN;
    float c0 = xc[h0c * 64 + px];
    float c1 = xc[h * 64 + px];
    float c2 = xc[h2c * 64 + px];
    c0 = v0 ? c0 : 0.f;
    c2 = v2 ? c2 : 0.f;
    float l0 = __shfl_up(c0, 1), l1 = __shfl_up(c1, 1), l2 = __shfl_up(c2, 1);
    float r0 = __shfl_down(c0, 1), r1 = __shfl_down(c1, 1),
          r2 = __shfl_down(c2, 1);
    l0 = e0 ? 0.f : l0;
    l1 = e0 ? 0.f : l1;
    l2 = e0 ? 0.f : l2;
    r0 = e63 ? 0.f : r0;
    r1 = e63 ? 0.f : r1;
    r2 = e63 ? 0.f : r2;
    float xv[9] = {l0, c0, r0, l1, c1, r1, l2, c2, r2};
    const int c = (cg << 5) + i;
    const float* owp = ow + c * 9;
    const float* mwp = mw + c * 9;
#pragma unroll
    for (int ch = 0; ch < 18; ++ch)
#pragma unroll
      for (int k = 0; k < 9; ++k)
        acc[ch] = fmaf(owp[ch * 2304 + k], xv[k], acc[ch]);
#pragma unroll
    for (int ch = 0; ch < 9; ++ch)
#pragma unroll
      for (int k = 0; k < 9; ++k)
        acc[18 + ch] = fmaf(mwp[ch * 2304 + k], xv[k], acc[18 + ch]);
  }

#pragma unroll
  for (int ch = 0; ch < 27; ++ch) ps[(px * 27 + ch) * 8 + cg] = acc[ch];
  __syncthreads();
  for (int i = tid; i < 1728; i += 512) {
    int p2 = i / 27;
    int ch = i - p2 * 27;
    float s = 0.f;
#pragma unroll
    for (int g = 0; g < 8; ++g) s += ps[i * 8 + g];
    if (ch < 18) {
      s += ob[ch];
      int k = ch >> 1;
      int o9 = ((b * 9 + k) << 12) + (h << 6) + p2;
      if ((ch & 1) == 0) dyb[o9] = s;
      else dxb[o9] = s;
    } else {
      int k = ch - 18;
      s += mb[k];
      mskb[((b * 9 + k) << 12) + (h << 6) + p2] = 2.f / (1.f + expf(-s));
    }
  }
}

__global__ __launch_bounds__(512, 4) void k_main_f32(
    const float* __restrict__ x, const unsigned short* __restrict__ wT,
    const float* __restrict__ dyb, const float* __restrict__ dxb,
    const float* __restrict__ mskb, float* __restrict__ out,
    float* __restrict__ psum, float* __restrict__ psq) {
  __shared__ __align__(16) char smem[50176];
  uint2* s_cw = (uint2*)smem;
  ushort4* s_ci = (ushort4*)(smem + 4608);
  char* sA = smem + 9216;
  char* sB = smem + 17408;
  float* tr = (float*)(smem + 9216);

  const int tid = threadIdx.x;
  const int mblk = blockIdx.x;
  const int b = mblk >> 6, h = mblk & 63;
  const int lane = tid & 63;
  const int wv = tid >> 6;

  for (int i = tid; i < 576; i += 512) {
    int k = i >> 6, pxi = i & 63;
    int o9 = ((b * 9 + k) << 12) + (h << 6) + pxi;
    float m = mskb[o9];
    float py = (float)(h - 1 + k / 3) + dyb[o9];
    float pxf = (float)(pxi - 1 + k % 3) + dxb[o9];
    float y0f = floorf(py), x0f = floorf(pxf);
    float wy = py - y0f, wx = pxf - x0f;
    int y0 = (int)y0f, x0 = (int)x0f;
    int y1 = y0 + 1, x1 = x0 + 1;
    float w00 = (1.f - wy) * (1.f - wx) * m;
    float w01 = (1.f - wy) * wx * m;
    float w10 = wy * (1.f - wx) * m;
    float w11 = wy * wx * m;
    bool vy0 = ((unsigned)y0 < 64u), vy1 = ((unsigned)y1 < 64u);
    bool vx0 = ((unsigned)x0 < 64u), vx1 = ((unsigned)x1 < 64u);
    if (!(vy0 && vx0)) w00 = 0.f;
    if (!(vy0 && vx1)) w01 = 0.f;
    if (!(vy1 && vx0)) w10 = 0.f;
    if (!(vy1 && vx1)) w11 = 0.f;
    int y0c = min(max(y0, 0), 63), y1c = min(max(y1, 0), 63);
    int x0c = min(max(x0, 0), 63), x1c = min(max(x1, 0), 63);
    s_cw[i] = make_uint2(pk2(w00, w01), pk2(w10, w11));
    s_ci[i] = make_ushort4((unsigned short)(y0c * 64 + x0c),
                           (unsigned short)(y0c * 64 + x1c),
                           (unsigned short)(y1c * 64 + x0c),
                           (unsigned short)(y1c * 64 + x1c));
  }
  __syncthreads();

  f32x4 acc[4][2];
#pragma unroll
  for (int mf = 0; mf < 4; ++mf)
#pragma unroll
    for (int nf = 0; nf < 2; ++nf) acc[mf][nf] = (f32x4){0.f, 0.f, 0.f, 0.f};

  const float* xb = x + b * (CI * HWN);
  const int aslot = (lane << 7) + ((wv ^ (lane & 7)) << 4);

  float rx[32];
  float4 cwC;
  {
    uint2 p = s_cw[lane];
    cwC.x = __uint_as_float(p.x << 16);
    cwC.y = __uint_as_float(p.x & 0xffff0000u);
    cwC.z = __uint_as_float(p.y << 16);
    cwC.w = __uint_as_float(p.y & 0xffff0000u);
    ushort4 ci0 = s_ci[lane];
    const float* xpn = xb + (wv << 3) * HWN;
#pragma unroll
    for (int s = 0; s < 8; ++s) {
      const float* xp = xpn + s * HWN;
      rx[4 * s + 0] = xp[ci0.x];
      rx[4 * s + 1] = xp[ci0.y];
      rx[4 * s + 2] = xp[ci0.z];
      rx[4 * s + 3] = xp[ci0.w];
    }
  }

#pragma unroll 1
  for (int t = 0; t < 36; ++t) {
    const int cq = t / 9;
    const int tap = t - cq * 9;
    {
      unsigned pkv[4];
#pragma unroll
      for (int j2 = 0; j2 < 4; ++j2) {
        float v0 = cwC.x * rx[8 * j2 + 0];
        v0 = fmaf(cwC.y, rx[8 * j2 + 1], v0);
        v0 = fmaf(cwC.z, rx[8 * j2 + 2], v0);
        v0 = fmaf(cwC.w, rx[8 * j2 + 3], v0);
        float v1 = cwC.x * rx[8 * j2 + 4];
        v1 = fmaf(cwC.y, rx[8 * j2 + 5], v1);
        v1 = fmaf(cwC.z, rx[8 * j2 + 6], v1);
        v1 = fmaf(cwC.w, rx[8 * j2 + 7], v1);
        pkv[j2] = pk2(v0, v1);
      }
      *(uint4*)(sA + aslot) = make_uint4(pkv[0], pkv[1], pkv[2], pkv[3]);
    }
    {
      const unsigned short* wp = wT + (tap << 16) + (cq << 6);
#pragma unroll
      for (int r = 0; r < 4; ++r) {
        int idx = (r << 9) + tid;
        int o = idx >> 3, seg = idx & 7;
        uint4 v = *(const uint4*)(wp + (o << 8) + (seg << 3));
        int slot = seg ^ (o & 7);
        *(uint4*)(sB + (o << 7) + (slot << 4)) = v;
      }
    }
    {
      const int tn = t < 35 ? t + 1 : 35;
      const int cqn = tn / 9;
      const int tapn = tn - cqn * 9;
      uint2 p = s_cw[(tapn << 6) + lane];
      float4 cwN;
      cwN.x = __uint_as_float(p.x << 16);
      cwN.y = __uint_as_float(p.x & 0xffff0000u);
      cwN.z = __uint_as_float(p.y << 16);
      cwN.w = __uint_as_float(p.y & 0xffff0000u);
      ushort4 ciN = s_ci[(tapn << 6) + lane];
      const float* xpn = xb + (((cqn << 3) + wv) << 3) * HWN;
#pragma unroll
      for (int s = 0; s < 8; ++s) {
        const float* xp = xpn + s * HWN;
        rx[4 * s + 0] = xp[ciN.x];
        rx[4 * s + 1] = xp[ciN.y];
        rx[4 * s + 2] = xp[ciN.z];
        rx[4 * s + 3] = xp[ciN.w];
      }
      cwC = cwN;
    }
    PIPE_BARRIER();
#pragma unroll
    for (int ks = 0; ks < 2; ++ks) {
      bf16x8 af[4], bfr[2];
#pragma unroll
      for (int mf = 0; mf < 4; ++mf) {
        int row = (mf << 4) + (lane & 15);
        int slot = ((ks << 2) + (lane >> 4)) ^ (row & 7);
        af[mf] = *(bf16x8*)(sA + (row << 7) + (slot << 4));
      }
#pragma unroll
      for (int nf = 0; nf < 2; ++nf) {
        int row = (wv << 5) + (nf << 4) + (lane & 15);
        int slot = ((ks << 2) + (lane >> 4)) ^ (row & 7);
        bfr[nf] = *(bf16x8*)(sB + (row << 7) + (slot << 4));
      }
#pragma unroll
      for (int mf = 0; mf < 4; ++mf)
#pragma unroll
        for (int nf = 0; nf < 2; ++nf)
          acc[mf][nf] = __builtin_amdgcn_mfma_f32_16x16x32_bf16(
              af[mf], bfr[nf], acc[mf][nf], 0, 0, 0);
    }
    PIPE_BARRIER();
  }

#pragma unroll
  for (int nf = 0; nf < 2; ++nf) {
    float s = 0.f, q = 0.f;
#pragma unroll
    for (int mf = 0; mf < 4; ++mf)
#pragma unroll
      for (int r = 0; r < 4; ++r) {
        float v = acc[mf][nf][r];
        s += v;
        q = fmaf(v, v, q);
      }
    s += __shfl_down(s, 32);
    q += __shfl_down(q, 32);
    s += __shfl_down(s, 16);
    q += __shfl_down(q, 16);
    if (lane < 16) {
      int o = (wv << 5) + (nf << 4) + lane;
      psum[(o << 9) + mblk] = s;
      psq[(o << 9) + mblk] = q;
    }
  }

  __syncthreads();
  for (int p = 0; p < 2; ++p) {
    if ((wv >> 2) == p) {
#pragma unroll
      for (int mf = 0; mf < 4; ++mf)
#pragma unroll
        for (int nf = 0; nf < 2; ++nf) {
          int ro = ((wv & 3) << 5) + (nf << 4) + (lane & 15);
#pragma unroll
          for (int r = 0; r < 4; ++r)
            tr[ro * 65 + (mf << 4) + ((lane >> 4) << 2) + r] = acc[mf][nf][r];
        }
    }
    __syncthreads();
#pragma unroll
    for (int it = 0; it < 4; ++it) {
      int idx = tid + (it << 9);
      int ro = idx >> 4, qd = idx & 15;
      float4 v = make_float4(tr[ro * 65 + qd * 4], tr[ro * 65 + qd * 4 + 1],
                             tr[ro * 65 + qd * 4 + 2], tr[ro * 65 + qd * 4 + 3]);
      *(float4*)(out + (((b << 8) + (p << 7) + ro) << 12) + (h << 6) +
                 (qd << 2)) = v;
    }
    __syncthreads();
  }
}

__global__ __launch_bounds__(64) void k_stats(
    const float* __restrict__ psum, const float* __restrict__ psq,
    const float* __restrict__ gamma, const float* __restrict__ beta,
    float* __restrict__ scale, float* __restrict__ shift) {
  const int o = blockIdx.x;
  const int t = threadIdx.x;
  float s = 0.f, q = 0.f;
#pragma unroll
  for (int i = 0; i < 8; ++i) {
    s += psum[(o << 9) + t + (i << 6)];
    q += psq[(o << 9) + t + (i << 6)];
  }
#pragma unroll
  for (int off = 32; off > 0; off >>= 1) {
    s += __shfl_down(s, off, 64);
    q += __shfl_down(q, off, 64);
  }
  if (t == 0) {
    const float inv_n = 1.f / 32768.f;
    float mean = s * inv_n;
    float var = fmaf(-mean, mean, q * inv_n);
    float sc = gamma[o] * rsqrtf(var + 1e-5f);
    scale[o] = sc;
    shift[o] = fmaf(-mean, sc, beta[o]);
  }
}

__global__ __launch_bounds__(256) void k_bnrelu(
    float* __restrict__ out, const float* __restrict__ scale,
    const float* __restrict__ shift) {
  int idx = blockIdx.x * 256 + threadIdx.x;
  int o = (idx >> 10) & 255;
  float sc = scale[o], sh = shift[o];
  float4 v = ((float4*)out)[idx];
  v.x = fmaxf(fmaf(v.x, sc, sh), 0.f);
  v.y = fmaxf(fmaf(v.y, sc, sh), 0.f);
  v.z = fmaxf(fmaf(v.z, sc, sh), 0.f);
  v.w = fmaxf(fmaf(v.w, sc, sh), 0.f);
  ((float4*)out)[idx] = v;
}

extern "C" void kernel_launch(void* const* d_in, const int* in_sizes, int n_in,
                              void* d_out, int out_size, void* d_ws,
                              size_t ws_size, hipStream_t stream) {
  const float* x = (const float*)d_in[0];
  const float* ow = (const float*)d_in[1];
  const float* ob = (const float*)d_in[2];
  const float* mw = (const float*)d_in[3];
  const float* mb = (const float*)d_in[4];
  const float* wgt = (const float*)d_in[5];
  // d_in[6] = conv bias: cancels exactly in BN (out - mean(out)), skipped.
  const float* gamma = (const float*)d_in[7];
  const float* beta = (const float*)d_in[8];
  float* out = (float*)d_out;

  float* ws = (float*)d_ws;
  float* dyb = ws;                  // 294912 (fallback only)
  float* dxb = dyb + 294912;        // 294912 (fallback only)
  float* mskb = dxb + 294912;       // 294912 (fallback only)
  float* psum = mskb + 294912;      // 131072
  float* psq = psum + 131072;       // 131072
  float* scale = psq + 131072;      // 256
  float* shift = scale + 256;       // 256
  unsigned short* wT = (unsigned short*)(shift + 256);  // 9*256*256 bf16
  unsigned short* xhp = wT + 589824;                    // 8.39M bf16
  unsigned short* wTo = xhp + 8388608;                  // 9*32*256 bf16
  const size_t WS_NEED = (size_t)(294912 * 3 + 131072 * 2 + 512) * 4 +
                         589824 * 2 + 8388608 * 2 + 73728 * 2;

  if (ws_size >= WS_NEED) {
    k_prep<<<4384, 256, 0, stream>>>(x, wgt, ow, mw, wT, wTo, xhp);
    k_fused2<<<512, 512, 0, stream>>>(xhp, wT, wTo, ob, mb, out, psum, psq);
  } else {
    k_wprep<<<256, 256, 0, stream>>>(wgt, wT);
    k_offmod_fb<<<512, 512, 0, stream>>>(x, ow, ob, mw, mb, dyb, dxb, mskb);
    k_main_f32<<<512, 512, 0, stream>>>(x, wT, dyb, dxb, mskb, out, psum, psq);
  }
  k_stats<<<256, 64, 0, stream>>>(psum, psq, gamma, beta, scale, shift);
  k_bnrelu<<<8192, 256, 0, stream>>>(out, scale, shift);
}